// Round 1
// baseline (62.196 us; speedup 1.0000x reference)
//
#include <hip/hip_runtime.h>
#include <math.h>

// QAM-64 straight-through vector quantizer.
// Forward output == hard = cb[argmin_m ||s - cb_m||^2] (soft terms cancel).
// Codebook is a separable 8x8 grid: m = i*8 + q, cbI_m = L[i], cbQ_m = L[q].
// => nearest point = per-axis nearest level, computed arithmetically:
//    idx = clamp(floor((s - L0)/Delta + 0.5), 0, 7);  hard = L0 + idx*Delta
// Boundary error ~3e-7 << reference fp32 distance noise (~1e-6) << threshold.
// Clip to [-2,2] is subsumed by the idx clamp (extreme levels |L|=1.08 < 2).
//
// v2 changes vs v1 (61.3 us measured):
//  - z loads issued FIRST (addresses independent of cb) so HBM latency
//    hides under the codebook preamble.
//  - power is separable: mean_64(x^2+y^2) = (sum_i LI_i^2 + sum_q LQ_q^2)/8.
//    16 uniform loads per thread, computed redundantly -> no LDS, no
//    __syncthreads, no serial tid==0 reduction.
//  - 16 floats/thread (4x float4 in flight) -> 512 blocks x 256 threads.

__global__ __launch_bounds__(256) void qam64_st_kernel(
    const float* __restrict__ z, const float* __restrict__ cb,
    float* __restrict__ out)
{
    // ---- issue all z loads up front ----
    // thread t: pair-id P = t>>7 (b*128+c), r = t&127, 8 I-elems + 8 Q-elems
    // I flat index = P*2048 + 8*r ; Q flat index = I + 1024. out same layout.
    const int t = blockIdx.x * 256 + threadIdx.x;
    const int P = t >> 7;
    const int r = t & 127;
    const size_t base = (size_t)P * 2048 + (size_t)(r * 8);

    const float4 vi0 = *(const float4*)(z + base);
    const float4 vi1 = *(const float4*)(z + base + 4);
    const float4 vq0 = *(const float4*)(z + base + 1024);
    const float4 vq1 = *(const float4*)(z + base + 1028);

    // ---- codebook preamble: reproduce reference's re-normalization ----
    // I-levels live at cb entries m=8*i -> cb[16*i]; Q-levels at cb[2*q+1].
    // All addresses wave-uniform -> scalar loads, overlap with vmcnt loads.
    float sI = 0.0f, sQ = 0.0f;
    #pragma unroll
    for (int k = 0; k < 8; ++k) {
        const float li = cb[16 * k];
        const float lq = cb[2 * k + 1];
        sI = fmaf(li, li, sI);
        sQ = fmaf(lq, lq, sQ);
    }
    const float power = (sI + sQ) * 0.125f;          // mean over 64 entries
    const float scale = sqrtf(1.0f / (power + 1e-8f)); // ~= 1.0

    const float L0I = cb[0]   * scale;
    const float L7I = cb[112] * scale;
    const float L0Q = cb[1]   * scale;
    const float L7Q = cb[15]  * scale;
    const float DI = (L7I - L0I) * (1.0f / 7.0f);
    const float DQ = (L7Q - L0Q) * (1.0f / 7.0f);
    const float invDI = 1.0f / DI;
    const float invDQ = 1.0f / DQ;
    const float CI = 0.5f - L0I * invDI;
    const float CQ = 0.5f - L0Q * invDQ;

    #define QUANT(s, invD, C, D, L0)                                   \
        fmaf(fminf(7.0f, fmaxf(0.0f, floorf(fmaf((s), (invD), (C))))), \
             (D), (L0))

    float4 oi0, oi1, oq0, oq1;
    oi0.x = QUANT(vi0.x, invDI, CI, DI, L0I);
    oi0.y = QUANT(vi0.y, invDI, CI, DI, L0I);
    oi0.z = QUANT(vi0.z, invDI, CI, DI, L0I);
    oi0.w = QUANT(vi0.w, invDI, CI, DI, L0I);
    oi1.x = QUANT(vi1.x, invDI, CI, DI, L0I);
    oi1.y = QUANT(vi1.y, invDI, CI, DI, L0I);
    oi1.z = QUANT(vi1.z, invDI, CI, DI, L0I);
    oi1.w = QUANT(vi1.w, invDI, CI, DI, L0I);
    oq0.x = QUANT(vq0.x, invDQ, CQ, DQ, L0Q);
    oq0.y = QUANT(vq0.y, invDQ, CQ, DQ, L0Q);
    oq0.z = QUANT(vq0.z, invDQ, CQ, DQ, L0Q);
    oq0.w = QUANT(vq0.w, invDQ, CQ, DQ, L0Q);
    oq1.x = QUANT(vq1.x, invDQ, CQ, DQ, L0Q);
    oq1.y = QUANT(vq1.y, invDQ, CQ, DQ, L0Q);
    oq1.z = QUANT(vq1.z, invDQ, CQ, DQ, L0Q);
    oq1.w = QUANT(vq1.w, invDQ, CQ, DQ, L0Q);
    #undef QUANT

    *(float4*)(out + base)        = oi0;
    *(float4*)(out + base + 4)    = oi1;
    *(float4*)(out + base + 1024) = oq0;
    *(float4*)(out + base + 1028) = oq1;
}

extern "C" void kernel_launch(void* const* d_in, const int* in_sizes, int n_in,
                              void* d_out, int out_size, void* d_ws, size_t ws_size,
                              hipStream_t stream) {
    const float* z  = (const float*)d_in[0];   // [8,256,32,32] fp32
    const float* cb = (const float*)d_in[1];   // [64,2] fp32
    float* out = (float*)d_out;                // [8,256,32,32] fp32

    // 2,097,152 elements total; 16 elements/thread -> 131,072 threads
    // = 512 blocks x 256 threads (2 blocks/CU on 256 CUs, 8 waves/CU).
    qam64_st_kernel<<<512, 256, 0, stream>>>(z, cb, out);
}